// Round 3
// baseline (502.001 us; speedup 1.0000x reference)
//
#include <hip/hip_runtime.h>
#include <hip/hip_fp16.h>

#define N_USERS 100000
#define M_ITEMS 50000
#define NNODES  (N_USERS + M_ITEMS)
#define EMBED   64
#define BATCH   8192

#define NU_E ((size_t)N_USERS * EMBED)
#define NE   ((size_t)NNODES * EMBED)    // 9,600,000 elements

#define NPB    256                        // nodes per perm bucket
#define NBUCK  ((NNODES + NPB - 1) / NPB) // 586
#define SCHUNK 2048                       // scan elems per block
#define SNB    ((NNODES + SCHUNK - 1) / SCHUNK) // 74
#define ZB     37                         // zero blocks: 37*4096 >= NNODES+1
#define PRED_BLOCKS ((BATCH * 64) / 256)  // 2048

typedef unsigned int uint;

static __device__ __forceinline__ ushort f2bf(float f) {
    uint u = __float_as_uint(f);
    return (ushort)((u + 0x7fffu + ((u >> 16) & 1u)) >> 16);
}
static __device__ __forceinline__ float bf_lo(uint u) { return __uint_as_float(u << 16); }
static __device__ __forceinline__ float bf_hi(uint u) { return __uint_as_float(u & 0xffff0000u); }
static __device__ __forceinline__ float bfs(ushort u) { return __uint_as_float((uint)u << 16); }

// packed edge: dst (17 bits, bipartite-local) << 15 | fp16(val) sans sign (val in [0,1))
static __device__ __forceinline__ int packe(int d, int fbits) {
    ushort h = __half_as_ushort(__float2half(__int_as_float(fbits)));
    return (int)(((uint)d << 15) | (uint)(h & 0x7fffu));
}
static __device__ __forceinline__ float unp_val(int p) {
    return __half2float(__ushort_as_half((ushort)(p & 0x7fff)));
}

// ---------------------------------------------------------------------------
// Fused: blocks [0,ZB) zero the degree/offs array; blocks [ZB,..) convert
// E0 = bf16(concat(eu0, ei0)).
// ---------------------------------------------------------------------------
__global__ void init_all(const float* __restrict__ eu, const float* __restrict__ ei,
                         ushort* __restrict__ E0, int* __restrict__ offs) {
    if (blockIdx.x < ZB) {
        int idx = (blockIdx.x * 1024 + threadIdx.x) * 4;
        if (idx + 3 < NNODES + 1) {
            *(int4*)(offs + idx) = make_int4(0, 0, 0, 0);
        } else {
            for (int k = 0; k < 4; ++k)
                if (idx + k < NNODES + 1) offs[idx + k] = 0;
        }
        return;
    }
    size_t t = (size_t)(blockIdx.x - ZB) * 1024 + threadIdx.x;
    const size_t nu4 = NU_E / 4;
    const size_t n4  = NE / 4;
    if (t >= n4) return;
    float4 v = (t < nu4) ? ((const float4*)eu)[t] : ((const float4*)ei)[t - nu4];
    ((ushort4*)E0)[t] = make_ushort4(f2bf(v.x), f2bf(v.y), f2bf(v.z), f2bf(v.w));
}

// ---------------------------------------------------------------------------
// Degree histogram: global atomics, ~16 collisions/counter, random spread.
// ---------------------------------------------------------------------------
__global__ void hist_deg(const int* __restrict__ src, int* __restrict__ offs, int nnz) {
    int i = blockIdx.x * blockDim.x + threadIdx.x;
    int stride = gridDim.x * blockDim.x;
    for (; i < nnz; i += stride)
        atomicAdd(&offs[src[i]], 1);
}

// ---------------------------------------------------------------------------
// Scan phase A: block-local exclusive scan of 2048 elems (256 thr x 8)
// ---------------------------------------------------------------------------
__global__ void scan_local(int* __restrict__ h, int* __restrict__ bsum, int n) {
    __shared__ int lds[256];
    const int tid = threadIdx.x;
    const int base = blockIdx.x * SCHUNK + tid * 8;
    int v[8]; int s = 0;
    #pragma unroll
    for (int c = 0; c < 8; ++c) { v[c] = (base + c < n) ? h[base + c] : 0; s += v[c]; }
    lds[tid] = s;
    __syncthreads();
    for (int off = 1; off < 256; off <<= 1) {
        int t = (tid >= off) ? lds[tid - off] : 0;
        __syncthreads();
        lds[tid] += t;
        __syncthreads();
    }
    if (tid == 255) bsum[blockIdx.x] = lds[255];
    int run = (tid > 0) ? lds[tid - 1] : 0;
    #pragma unroll
    for (int c = 0; c < 8; ++c) {
        int t = v[c];
        if (base + c < n) h[base + c] = run;
        run += t;
    }
}

// ---------------------------------------------------------------------------
// Scan phase B+C fused: re-scan bsum in LDS, add block prefix; also emit the
// mutable cursor copy for the scatter, and offs[n] = nnz.
// ---------------------------------------------------------------------------
__global__ void scan_add2(int* __restrict__ h, const int* __restrict__ bsum,
                          int* __restrict__ cur, int n, int nblk, int nnz) {
    __shared__ int lds[256];
    int tid = threadIdx.x;
    if (tid < 256) lds[tid] = (tid < nblk) ? bsum[tid] : 0;
    __syncthreads();
    for (int off = 1; off < 256; off <<= 1) {
        int t = (tid >= off && tid < 256) ? lds[tid - off] : 0;
        __syncthreads();
        if (tid < 256) lds[tid] += t;
        __syncthreads();
    }
    int prefix = (blockIdx.x > 0) ? lds[blockIdx.x - 1] : 0;
    int lim = min(blockIdx.x * SCHUNK + SCHUNK, n);
    for (int i = blockIdx.x * SCHUNK + tid; i < lim; i += 1024) {
        int v = h[i] + prefix;
        h[i] = v;
        cur[i] = v;
    }
    if (blockIdx.x == 0 && tid == 0) h[n] = nnz;
}

// ---------------------------------------------------------------------------
// Scatter edges straight into CSR slots via global atomic cursors.
// ---------------------------------------------------------------------------
__global__ void scatter_ep(const int* __restrict__ src, const int* __restrict__ dst,
                           const float* __restrict__ vals,
                           int* __restrict__ cur, int* __restrict__ ep, int nnz) {
    int i = blockIdx.x * blockDim.x + threadIdx.x;
    int stride = gridDim.x * blockDim.x;
    for (; i < nnz; i += stride) {
        int sv = src[i];
        int d  = dst[i];
        float v = vals[i];
        if (d >= N_USERS) d -= N_USERS;          // bipartite-local dst index
        int p = atomicAdd(&cur[sv], 1);
        ep[p] = packe(d, __float_as_int(v));
    }
}

// ---------------------------------------------------------------------------
// Per 256-node bucket: offs2 = {start, deg}; ascending-degree perm (LDS
// counting sort) — identical semantics to the old bucket_sort_perm tail.
// ---------------------------------------------------------------------------
__global__ void __launch_bounds__(256)
perm_offs2(const int* __restrict__ offs, int2* __restrict__ offs2,
           int* __restrict__ perm) {
    __shared__ int sc[256], dsc[256], cur[256];
    int b = blockIdx.x, tid = threadIdx.x;
    int node = b * NPB + tid;
    int nodeCount = min(NNODES - b * NPB, NPB);
    int deg = 0;
    if (tid < nodeCount) {
        int st = offs[node];
        deg = offs[node + 1] - st;
        offs2[node] = make_int2(st, deg);
    }
    int bin = min(deg, 255);
    sc[tid] = 0;
    __syncthreads();
    if (tid < nodeCount) atomicAdd(&sc[bin], 1);
    __syncthreads();
    dsc[tid] = sc[tid];
    __syncthreads();
    for (int off = 1; off < 256; off <<= 1) {
        int t = (tid >= off) ? dsc[tid - off] : 0;
        __syncthreads();
        dsc[tid] += t;
        __syncthreads();
    }
    cur[tid] = b * NPB + ((tid > 0) ? dsc[tid - 1] : 0);
    __syncthreads();
    if (tid < nodeCount) {
        int rank = atomicAdd(&cur[bin], 1);
        perm[rank] = node;
    }
}

// ---------------------------------------------------------------------------
// Gather layer (UNCHANGED control group): Enext[node] = sum val * Eprev[dst]
// 8 nodes/wave (degree-sorted), 8 lanes/node, branch-free unroll-8.
// ---------------------------------------------------------------------------
__global__ void gather_E(const int2* __restrict__ offs2, const int* __restrict__ ep,
                         const int* __restrict__ perm,
                         const ushort* __restrict__ Eprev, ushort* __restrict__ Enext) {
    int t = blockIdx.x * blockDim.x + threadIdx.x;
    int wave = t >> 6;
    int lane = t & 63;
    int g = lane >> 3;
    int q = lane & 7;
    int ln = wave * 8 + g;
    bool valid = ln < NNODES;
    int node = valid ? perm[ln] : 0;
    int2 od = valid ? offs2[node] : make_int2(0, 0);
    int start = od.x;
    int deg   = od.y;
    const uint4* other = (const uint4*)(Eprev + (node < N_USERS ? NU_E : 0));
    int lastIdx = max(start + deg - 1, 0);

    int md = deg;
    #pragma unroll
    for (int off = 8; off <= 32; off <<= 1) md = max(md, __shfl_xor(md, off));

    float a0=0.f,a1=0.f,a2=0.f,a3=0.f,a4=0.f,a5=0.f,a6=0.f,a7=0.f;
    for (int k = 0; k < md; k += 8) {
        int e[8];
        uint4 r[8];
        #pragma unroll
        for (int c = 0; c < 8; ++c) {
            int idx = (k + c < deg) ? start + k + c : lastIdx;
            e[c] = ep[idx];
            if (k + c >= deg) e[c] = 0;           // dst=0 (hot line), val=+0.0
        }
        #pragma unroll
        for (int c = 0; c < 8; ++c)
            r[c] = other[(size_t)(((uint)e[c]) >> 15) * 8 + q];
        #pragma unroll
        for (int c = 0; c < 8; ++c) {
            float v = unp_val(e[c]);
            a0 = fmaf(v, bf_lo(r[c].x), a0);  a1 = fmaf(v, bf_hi(r[c].x), a1);
            a2 = fmaf(v, bf_lo(r[c].y), a2);  a3 = fmaf(v, bf_hi(r[c].y), a3);
            a4 = fmaf(v, bf_lo(r[c].z), a4);  a5 = fmaf(v, bf_hi(r[c].z), a5);
            a6 = fmaf(v, bf_lo(r[c].w), a6);  a7 = fmaf(v, bf_hi(r[c].w), a7);
        }
    }

    if (!valid) return;
    uint4 o;
    o.x = (uint)f2bf(a0) | ((uint)f2bf(a1) << 16);
    o.y = (uint)f2bf(a2) | ((uint)f2bf(a3) << 16);
    o.z = (uint)f2bf(a4) | ((uint)f2bf(a5) << 16);
    o.w = (uint)f2bf(a6) | ((uint)f2bf(a7) << 16);
    ((uint4*)Enext)[(size_t)node * 8 + q] = o;
}

// ---------------------------------------------------------------------------
// Predict: sum 4 generations of bf16 rows, dot, /16; reg-loss block partials.
// ---------------------------------------------------------------------------
__global__ void predict_kernel(const int* __restrict__ user, const int* __restrict__ item_i,
                               const int* __restrict__ item_j,
                               const ushort* __restrict__ E0, const ushort* __restrict__ E1,
                               const ushort* __restrict__ E2, const ushort* __restrict__ E3,
                               const float* __restrict__ eu0, const float* __restrict__ ei0,
                               float* __restrict__ out, float* __restrict__ rbuf) {
    __shared__ float rpart[4];
    int t = blockIdx.x * blockDim.x + threadIdx.x;
    int b = t >> 6;
    int d = t & 63;
    int wv = threadIdx.x >> 6;
    float pi = 0.f, pj = 0.f, r = 0.f;
    if (b < BATCH) {
        size_t ru = (size_t)user[b] * EMBED + d;
        size_t ri = ((size_t)N_USERS + item_i[b]) * EMBED + d;
        size_t rj = ((size_t)N_USERS + item_j[b]) * EMBED + d;
        float ue = bfs(E0[ru]) + bfs(E1[ru]) + bfs(E2[ru]) + bfs(E3[ru]);
        float ie = bfs(E0[ri]) + bfs(E1[ri]) + bfs(E2[ri]) + bfs(E3[ri]);
        float je = bfs(E0[rj]) + bfs(E1[rj]) + bfs(E2[rj]) + bfs(E3[rj]);
        pi = ue * ie;
        pj = ue * je;
        float u0 = eu0[(size_t)user[b] * EMBED + d];
        float i0 = ei0[(size_t)item_i[b] * EMBED + d];
        float j0 = ei0[(size_t)item_j[b] * EMBED + d];
        r = u0 * u0 + i0 * i0 + j0 * j0;
    }
    #pragma unroll
    for (int off = 32; off > 0; off >>= 1) {
        pi += __shfl_down(pi, off);
        pj += __shfl_down(pj, off);
        r  += __shfl_down(r,  off);
    }
    if (d == 0 && b < BATCH) {
        out[b]         = pi * (1.0f / 16.0f);
        out[BATCH + b] = pj * (1.0f / 16.0f);
        rpart[wv] = r;
    }
    __syncthreads();
    if (threadIdx.x == 0)
        rbuf[blockIdx.x] = rpart[0] + rpart[1] + rpart[2] + rpart[3];
}

__global__ void finalize_reg(const float* __restrict__ rbuf, float* __restrict__ out) {
    __shared__ float lds[4];
    int tid = threadIdx.x;
    float s = 0.f;
    for (int i = tid; i < PRED_BLOCKS; i += 256) s += rbuf[i];
    #pragma unroll
    for (int off = 32; off > 0; off >>= 1) s += __shfl_down(s, off);
    if ((tid & 63) == 0) lds[tid >> 6] = s;
    __syncthreads();
    if (tid == 0)
        out[2 * BATCH] = (lds[0] + lds[1] + lds[2] + lds[3]) * (0.5f / (float)BATCH);
}

// ---------------------------------------------------------------------------
extern "C" void kernel_launch(void* const* d_in, const int* in_sizes, int n_in,
                              void* d_out, int out_size, void* d_ws, size_t ws_size,
                              hipStream_t stream) {
    const int*   user      = (const int*)  d_in[0];
    const int*   item_i    = (const int*)  d_in[1];
    const int*   item_j    = (const int*)  d_in[2];
    const int*   edge_src  = (const int*)  d_in[5];
    const int*   edge_dst  = (const int*)  d_in[6];
    const float* edge_vals = (const float*)d_in[7];
    const float* eu0       = (const float*)d_in[8];
    const float* ei0       = (const float*)d_in[9];
    const int    nnz       = in_sizes[5];

    float* out = (float*)d_out;

    // ---- workspace (~89 MB) ----
    ushort* E0    = (ushort*)d_ws;               // 19.2 MB each
    ushort* E1    = E0 + NE;
    ushort* E2    = E1 + NE;
    ushort* E3    = E2 + NE;
    int*    ep    = (int*)(E3 + NE);             // nnz packed edges, 9.6 MB
    int*    offs  = ep + nnz;                    // NNODES+2 (padded even)
    int*    cur   = offs + NNODES + 2;           // NNODES mutable cursors
    int2*   offs2 = (int2*)(cur + NNODES);       // {start, deg} per node (8B-aligned)
    int*    perm  = (int*)(offs2 + NNODES);      // NNODES
    int*    bsum  = perm + NNODES;               // SNB (74), pad 256
    float*  rbuf  = (float*)(bsum + 256);        // PRED_BLOCKS

    const int initBlocks = (int)((NE / 4 + 1023) / 1024);   // 2344

    // 1) fused zero(offs) + E0 = bf16(concat)
    init_all<<<ZB + initBlocks, 1024, 0, stream>>>(eu0, ei0, E0, offs);
    // 2) degree histogram (global atomics)
    hist_deg<<<2048, 256, 0, stream>>>(edge_src, offs, nnz);
    // 3-4) scan degrees -> offs (+ cursor copy)
    scan_local<<<SNB, 256, 0, stream>>>(offs, bsum, NNODES);
    scan_add2<<<SNB, 1024, 0, stream>>>(offs, bsum, cur, NNODES, SNB, nnz);
    // 5) scatter edges into CSR slots (packed 4B)
    scatter_ep<<<2048, 256, 0, stream>>>(edge_src, edge_dst, edge_vals, cur, ep, nnz);
    // 6) per-bucket {start,deg} + ascending-degree perm
    perm_offs2<<<NBUCK, 256, 0, stream>>>(offs, offs2, perm);
    // 7-9) propagation layers
    const int gblocks = (int)((((NNODES + 7) / 8) * 64 + 255) / 256);
    gather_E<<<gblocks, 256, 0, stream>>>(offs2, ep, perm, E0, E1);
    gather_E<<<gblocks, 256, 0, stream>>>(offs2, ep, perm, E1, E2);
    gather_E<<<gblocks, 256, 0, stream>>>(offs2, ep, perm, E2, E3);
    // 10-11) predictions + reg loss
    predict_kernel<<<PRED_BLOCKS, 256, 0, stream>>>(
        user, item_i, item_j, E0, E1, E2, E3, eu0, ei0, out, rbuf);
    finalize_reg<<<1, 256, 0, stream>>>(rbuf, out);
}

// Round 4
// 307.475 us; speedup vs baseline: 1.6327x; 1.6327x over previous
//
#include <hip/hip_runtime.h>
#include <hip/hip_fp16.h>

#define N_USERS 100000
#define M_ITEMS 50000
#define NNODES  (N_USERS + M_ITEMS)
#define EMBED   64
#define BATCH   8192

#define NU_E ((size_t)N_USERS * EMBED)
#define NE   ((size_t)NNODES * EMBED)    // 9,600,000 elements

#define NPB    256                        // nodes per CSR bucket
#define NBUCK  ((NNODES + NPB - 1) / NPB) // 586
#define CAP    8192                       // fixed edge-slot region per bucket
#define CSTR   16                         // cursor padding stride (ints)
#define PBLK   512                        // partition blocks
#define PTILE  4688                       // edges per block
#define BCAP   12288                      // packed ints staged in LDS (48 KB)
#define PRED_BLOCKS ((BATCH * 64) / 256)  // 2048

typedef unsigned int uint;

static __device__ __forceinline__ ushort f2bf(float f) {
    uint u = __float_as_uint(f);
    return (ushort)((u + 0x7fffu + ((u >> 16) & 1u)) >> 16);
}
static __device__ __forceinline__ float bf_lo(uint u) { return __uint_as_float(u << 16); }
static __device__ __forceinline__ float bf_hi(uint u) { return __uint_as_float(u & 0xffff0000u); }
static __device__ __forceinline__ float bfs(ushort u) { return __uint_as_float((uint)u << 16); }

// packed edge: dst (17 bits, bipartite-local) << 15 | fp16(val) sans sign (val in [0,1))
static __device__ __forceinline__ int packe(int d, int fbits) {
    ushort h = __half_as_ushort(__float2half(__int_as_float(fbits)));
    return (int)(((uint)d << 15) | (uint)(h & 0x7fffu));
}
static __device__ __forceinline__ float unp_val(int p) {
    return __half2float(__ushort_as_half((ushort)(p & 0x7fff)));
}

// ---------------------------------------------------------------------------
// Fused: block 0 inits per-bucket global cursors to b*CAP;
//        blocks [1,..) = E0 = bf16(concat(eu0, ei0)).
// ---------------------------------------------------------------------------
__global__ void init_all(const float* __restrict__ eu, const float* __restrict__ ei,
                         ushort* __restrict__ E0, int* __restrict__ gcur) {
    if (blockIdx.x == 0) {
        for (int i = threadIdx.x; i < NBUCK; i += 1024) gcur[i * CSTR] = i * CAP;
        return;
    }
    size_t t = (size_t)(blockIdx.x - 1) * 1024 + threadIdx.x;
    const size_t nu4 = NU_E / 4;
    const size_t n4  = NE / 4;
    if (t >= n4) return;
    float4 v = (t < nu4) ? ((const float4*)eu)[t] : ((const float4*)ei)[t - nu4];
    ((ushort4*)E0)[t] = make_ushort4(f2bf(v.x), f2bf(v.y), f2bf(v.z), f2bf(v.w));
}

// ---------------------------------------------------------------------------
// Partition: single LDS pass per block (PTILE edges), LDS counting sort by
// bucket, contiguous run write-out into CAP-padded bucket regions (atomic
// run reservation). Scans are wave-shfl based: 2 barriers, not 20.
// ---------------------------------------------------------------------------
__global__ void __launch_bounds__(1024)
partition2(const int* __restrict__ src, const int* __restrict__ dst,
           const float* __restrict__ vals, int* __restrict__ gcur,
           int2* __restrict__ ebuf, int nnz) {
    __shared__ int2 data[PTILE];      // 37.5 KB
    __shared__ int  cnt[NBUCK];
    __shared__ int  cur[NBUCK];
    __shared__ int  lbeg[NBUCK];
    __shared__ int  gbase[NBUCK];
    __shared__ int  wsum[16];
    const int blk = blockIdx.x;
    const int tid = threadIdx.x;
    const int lane = tid & 63, w = tid >> 6;
    const int base = blk * PTILE;
    const int end  = min(base + PTILE, nnz);

    for (int i = tid; i < NBUCK; i += 1024) cnt[i] = 0;
    __syncthreads();
    for (int i = base + tid; i < end; i += 1024)
        atomicAdd(&cnt[src[i] >> 8], 1);
    __syncthreads();
    // ---- wave-shfl exclusive scan over cnt[0..NBUCK) ----
    int c = (tid < NBUCK) ? cnt[tid] : 0;
    int v = c;
    #pragma unroll
    for (int off = 1; off < 64; off <<= 1) {
        int t = __shfl_up(v, off);
        if (lane >= off) v += t;
    }
    if (lane == 63) wsum[w] = v;
    __syncthreads();
    int wpre = 0;
    #pragma unroll
    for (int k = 0; k < 16; ++k) wpre += (k < w) ? wsum[k] : 0;
    v += wpre;                                   // inclusive prefix
    if (tid < NBUCK) {
        int ex = v - c;
        cur[tid]  = ex;                          // mutable cursor
        lbeg[tid] = ex;                          // stable run start
        if (c > 0) gbase[tid] = atomicAdd(&gcur[tid * CSTR], c);
    }
    __syncthreads();
    for (int i = base + tid; i < end; i += 1024) {
        int sv = src[i];
        int d  = dst[i];
        float fv = vals[i];
        if (d >= N_USERS) d -= N_USERS;          // bipartite-local dst index
        int p = atomicAdd(&cur[sv >> 8], 1);
        data[p] = make_int2((sv & 255) | (d << 8), __float_as_int(fv));
    }
    __syncthreads();
    int grp = tid >> 4, lane16 = tid & 15;        // 64 groups of 16
    for (int b = grp; b < NBUCK; b += 64) {
        int cc = cnt[b];
        if (cc == 0) continue;
        int lb = lbeg[b];
        int gb = gbase[b];
        for (int j = lane16; j < cc; j += 16)
            ebuf[gb + j] = data[lb + j];
    }
}

// ---------------------------------------------------------------------------
// One block per bucket: LDS node counts + wave-shfl scan -> offs2 {start,deg},
// LDS-staged node sort -> contiguous packed ep (4 B/edge), + DESCENDING-degree
// perm (big nodes scheduled first; tail = tiny nodes).
// ---------------------------------------------------------------------------
__global__ void __launch_bounds__(1024)
bucket_sort_perm(const int* __restrict__ gcur, const int2* __restrict__ ebuf,
                 int2* __restrict__ offs2, int* __restrict__ ep,
                 int* __restrict__ perm) {
    __shared__ int data[BCAP];        // 48 KB (packed)
    __shared__ int cnt[256], cur[256], bcnt[256];
    __shared__ int wsum[16];
    int b   = blockIdx.x;
    int tid = threadIdx.x;
    int lane = tid & 63, w = tid >> 6;
    int beg = b * CAP;
    int end = gcur[b * CSTR];         // = beg + bucket_len after partition
    int blen = end - beg;
    if (tid < 256) cnt[tid] = 0;
    __syncthreads();
    for (int i = beg + tid; i < end; i += 1024)
        atomicAdd(&cnt[ebuf[i].x & 255], 1);
    __syncthreads();
    // ---- wave-shfl scan over cnt[0..256) (waves 0..3) ----
    int c = (tid < 256) ? cnt[tid] : 0;
    int v = c;
    #pragma unroll
    for (int off = 1; off < 64; off <<= 1) {
        int t = __shfl_up(v, off);
        if (lane >= off) v += t;
    }
    if (tid < 256 && lane == 63) wsum[w] = v;
    __syncthreads();
    if (tid < 256) {
        int wpre = 0;
        #pragma unroll
        for (int k = 0; k < 4; ++k) wpre += (k < w) ? wsum[k] : 0;
        v += wpre;
        int lbase = v - c;                         // exclusive
        int node = b * NPB + tid;
        if (node < NNODES) offs2[node] = make_int2(beg + lbase, c);
        cur[tid] = lbase;
    }
    __syncthreads();
    if (blen <= BCAP) {
        for (int i = beg + tid; i < end; i += 1024) {
            int2 e = ebuf[i];
            int p = atomicAdd(&cur[e.x & 255], 1);
            data[p] = packe(e.x >> 8, e.y);
        }
        __syncthreads();
        for (int i = tid; i < blen; i += 1024)
            ep[beg + i] = data[i];
    } else {
        for (int i = beg + tid; i < end; i += 1024) {
            int2 e = ebuf[i];
            int p = atomicAdd(&cur[e.x & 255], 1);
            ep[beg + p] = packe(e.x >> 8, e.y);
        }
    }
    // ---- perm: counting sort by DESCENDING degree ----
    __syncthreads();
    if (tid < 256) bcnt[tid] = 0;
    __syncthreads();
    int nodeCount = min(NNODES - b * NPB, NPB);
    int bin = 0;
    if (tid < nodeCount) {
        bin = 255 - min(cnt[tid], 255);            // descending order
        atomicAdd(&bcnt[bin], 1);
    }
    __syncthreads();
    int c2 = (tid < 256) ? bcnt[tid] : 0;
    int v2 = c2;
    #pragma unroll
    for (int off = 1; off < 64; off <<= 1) {
        int t = __shfl_up(v2, off);
        if (lane >= off) v2 += t;
    }
    if (tid < 256 && lane == 63) wsum[w] = v2;
    __syncthreads();
    if (tid < 256) {
        int wpre = 0;
        #pragma unroll
        for (int k = 0; k < 4; ++k) wpre += (k < w) ? wsum[k] : 0;
        v2 += wpre;
        cur[tid] = b * NPB + (v2 - c2);
    }
    __syncthreads();
    if (tid < nodeCount) {
        int rank = atomicAdd(&cur[bin], 1);
        perm[rank] = b * NPB + tid;
    }
}

// ---------------------------------------------------------------------------
// Gather layer: Enext[node] = sum val * Eprev[dst]
// 8 nodes/wave (degree-sorted desc), 8 lanes/node, branch-free unroll-16
// (16 outstanding row loads/lane for latency hiding).
// ---------------------------------------------------------------------------
__global__ void gather_E(const int2* __restrict__ offs2, const int* __restrict__ ep,
                         const int* __restrict__ perm,
                         const ushort* __restrict__ Eprev, ushort* __restrict__ Enext) {
    int t = blockIdx.x * blockDim.x + threadIdx.x;
    int wave = t >> 6;
    int lane = t & 63;
    int g = lane >> 3;
    int q = lane & 7;
    int ln = wave * 8 + g;
    bool valid = ln < NNODES;
    int node = valid ? perm[ln] : 0;
    int2 od = valid ? offs2[node] : make_int2(0, 0);
    int start = od.x;
    int deg   = od.y;
    const uint4* other = (const uint4*)(Eprev + (node < N_USERS ? NU_E : 0));
    int lastIdx = max(start + deg - 1, 0);

    int md = deg;
    #pragma unroll
    for (int off = 8; off <= 32; off <<= 1) md = max(md, __shfl_xor(md, off));

    float a0=0.f,a1=0.f,a2=0.f,a3=0.f,a4=0.f,a5=0.f,a6=0.f,a7=0.f;
    for (int k = 0; k < md; k += 16) {
        int e[16];
        uint4 r[16];
        #pragma unroll
        for (int c = 0; c < 16; ++c) {
            int idx = (k + c < deg) ? start + k + c : lastIdx;
            e[c] = ep[idx];
            if (k + c >= deg) e[c] = 0;           // dst=0 (hot line), val=+0.0
        }
        #pragma unroll
        for (int c = 0; c < 16; ++c)
            r[c] = other[(size_t)(((uint)e[c]) >> 15) * 8 + q];
        #pragma unroll
        for (int c = 0; c < 16; ++c) {
            float v = unp_val(e[c]);
            a0 = fmaf(v, bf_lo(r[c].x), a0);  a1 = fmaf(v, bf_hi(r[c].x), a1);
            a2 = fmaf(v, bf_lo(r[c].y), a2);  a3 = fmaf(v, bf_hi(r[c].y), a3);
            a4 = fmaf(v, bf_lo(r[c].z), a4);  a5 = fmaf(v, bf_hi(r[c].z), a5);
            a6 = fmaf(v, bf_lo(r[c].w), a6);  a7 = fmaf(v, bf_hi(r[c].w), a7);
        }
    }

    if (!valid) return;
    uint4 o;
    o.x = (uint)f2bf(a0) | ((uint)f2bf(a1) << 16);
    o.y = (uint)f2bf(a2) | ((uint)f2bf(a3) << 16);
    o.z = (uint)f2bf(a4) | ((uint)f2bf(a5) << 16);
    o.w = (uint)f2bf(a6) | ((uint)f2bf(a7) << 16);
    ((uint4*)Enext)[(size_t)node * 8 + q] = o;
}

// ---------------------------------------------------------------------------
// Predict: sum 4 generations of bf16 rows, dot, /16; reg-loss block partials.
// ---------------------------------------------------------------------------
__global__ void predict_kernel(const int* __restrict__ user, const int* __restrict__ item_i,
                               const int* __restrict__ item_j,
                               const ushort* __restrict__ E0, const ushort* __restrict__ E1,
                               const ushort* __restrict__ E2, const ushort* __restrict__ E3,
                               const float* __restrict__ eu0, const float* __restrict__ ei0,
                               float* __restrict__ out, float* __restrict__ rbuf) {
    __shared__ float rpart[4];
    int t = blockIdx.x * blockDim.x + threadIdx.x;
    int b = t >> 6;
    int d = t & 63;
    int wv = threadIdx.x >> 6;
    float pi = 0.f, pj = 0.f, r = 0.f;
    if (b < BATCH) {
        size_t ru = (size_t)user[b] * EMBED + d;
        size_t ri = ((size_t)N_USERS + item_i[b]) * EMBED + d;
        size_t rj = ((size_t)N_USERS + item_j[b]) * EMBED + d;
        float ue = bfs(E0[ru]) + bfs(E1[ru]) + bfs(E2[ru]) + bfs(E3[ru]);
        float ie = bfs(E0[ri]) + bfs(E1[ri]) + bfs(E2[ri]) + bfs(E3[ri]);
        float je = bfs(E0[rj]) + bfs(E1[rj]) + bfs(E2[rj]) + bfs(E3[rj]);
        pi = ue * ie;
        pj = ue * je;
        float u0 = eu0[(size_t)user[b] * EMBED + d];
        float i0 = ei0[(size_t)item_i[b] * EMBED + d];
        float j0 = ei0[(size_t)item_j[b] * EMBED + d];
        r = u0 * u0 + i0 * i0 + j0 * j0;
    }
    #pragma unroll
    for (int off = 32; off > 0; off >>= 1) {
        pi += __shfl_down(pi, off);
        pj += __shfl_down(pj, off);
        r  += __shfl_down(r,  off);
    }
    if (d == 0 && b < BATCH) {
        out[b]         = pi * (1.0f / 16.0f);
        out[BATCH + b] = pj * (1.0f / 16.0f);
        rpart[wv] = r;
    }
    __syncthreads();
    if (threadIdx.x == 0)
        rbuf[blockIdx.x] = rpart[0] + rpart[1] + rpart[2] + rpart[3];
}

__global__ void finalize_reg(const float* __restrict__ rbuf, float* __restrict__ out) {
    __shared__ float lds[4];
    int tid = threadIdx.x;
    float s = 0.f;
    for (int i = tid; i < PRED_BLOCKS; i += 256) s += rbuf[i];
    #pragma unroll
    for (int off = 32; off > 0; off >>= 1) s += __shfl_down(s, off);
    if ((tid & 63) == 0) lds[tid >> 6] = s;
    __syncthreads();
    if (tid == 0)
        out[2 * BATCH] = (lds[0] + lds[1] + lds[2] + lds[3]) * (0.5f / (float)BATCH);
}

// ---------------------------------------------------------------------------
extern "C" void kernel_launch(void* const* d_in, const int* in_sizes, int n_in,
                              void* d_out, int out_size, void* d_ws, size_t ws_size,
                              hipStream_t stream) {
    const int*   user      = (const int*)  d_in[0];
    const int*   item_i    = (const int*)  d_in[1];
    const int*   item_j    = (const int*)  d_in[2];
    const int*   edge_src  = (const int*)  d_in[5];
    const int*   edge_dst  = (const int*)  d_in[6];
    const float* edge_vals = (const float*)d_in[7];
    const float* eu0       = (const float*)d_in[8];
    const float* ei0       = (const float*)d_in[9];
    const int    nnz       = in_sizes[5];

    float* out = (float*)d_out;

    // ---- workspace (~98 MB) ----
    ushort* E0    = (ushort*)d_ws;               // 19.2 MB each
    ushort* E1    = E0 + NE;
    ushort* E2    = E1 + NE;
    ushort* E3    = E2 + NE;
    int*    ep    = (int*)(E3 + NE);             // NBUCK*CAP packed edges, 19.2 MB
    int2*   offs2 = (int2*)(ep + (size_t)NBUCK * CAP); // {start, deg} per node
    int*    gcur  = (int*)(offs2 + NNODES);      // NBUCK padded cursors (1/line)
    int*    perm  = gcur + NBUCK * CSTR;         // NNODES
    float*  rbuf  = (float*)(perm + NNODES);     // PRED_BLOCKS
    // ebuf spans E1+E2 (+4 KB into E3's head); all dead before their writers run
    int2*   ebuf  = (int2*)E1;

    const int initBlocks = (int)((NE / 4 + 1023) / 1024);   // 2344

    // 1) fused cursor-init + E0 = bf16(concat)
    init_all<<<1 + initBlocks, 1024, 0, stream>>>(eu0, ei0, E0, gcur);
    // 2) single-pass LDS partition into CAP-padded bucket runs (atomic reserve)
    partition2<<<PBLK, 1024, 0, stream>>>(edge_src, edge_dst, edge_vals,
                                          gcur, ebuf, nnz);
    // 3) node sort + offs2 + contiguous packed ep + descending-degree perm
    bucket_sort_perm<<<NBUCK, 1024, 0, stream>>>(gcur, ebuf, offs2, ep, perm);
    // 4-6) propagation layers
    const int gblocks = (int)((((NNODES + 7) / 8) * 64 + 255) / 256);
    gather_E<<<gblocks, 256, 0, stream>>>(offs2, ep, perm, E0, E1);
    gather_E<<<gblocks, 256, 0, stream>>>(offs2, ep, perm, E1, E2);
    gather_E<<<gblocks, 256, 0, stream>>>(offs2, ep, perm, E2, E3);
    // 7-8) predictions + reg loss
    predict_kernel<<<PRED_BLOCKS, 256, 0, stream>>>(
        user, item_i, item_j, E0, E1, E2, E3, eu0, ei0, out, rbuf);
    finalize_reg<<<1, 256, 0, stream>>>(rbuf, out);
}